// Round 11
// baseline (793.058 us; speedup 1.0000x reference)
//
#include <hip/hip_runtime.h>
#include <hip/hip_bf16.h>

#define K_CODES 8192
#define DIM     512
#define N_VEC   32768
// flag threshold on g = x.e - e2/2 : bf16-dot error budget (~0.35) plus
// 11-bit packed-tag quantization (<=0.0625 for |g|<512). Near-ties are
// rescued exactly; MARGIN affects rescue count, not correctness. (r3-proven)
#define MARGIN  0.5f

typedef __attribute__((ext_vector_type(8)))  short  short8;    // bf16x8 MFMA operand
typedef __attribute__((ext_vector_type(8)))  unsigned short ushort8;
typedef __attribute__((ext_vector_type(16))) float  float16x;  // 32x32 MFMA C/D frag

// async global->LDS, 16 B/lane. LDS dest = wave-uniform base + lane*16.
__device__ inline void gl_lds16(const void* g, void* l) {
    __builtin_amdgcn_global_load_lds(
        (const __attribute__((address_space(1))) unsigned int*)g,
        (__attribute__((address_space(3))) unsigned int*)l, 16, 0, 0);
}

// fp32 -> bf16 bits, round-to-nearest-even
__device__ inline unsigned short f2bf(float f) {
    unsigned int u = __float_as_uint(f);
    return (unsigned short)((u + 0x7FFFu + ((u >> 16) & 1u)) >> 16);
}

__device__ inline float med3(float a, float b, float c) {
    return __builtin_amdgcn_fmed3f(a, b, c);
}

// ---------------------------------------------------------------------------
// Kernel 1: prep. rows [0,N_VEC) from z -> zh + x2 ; rows [N_VEC,+K) from cb
// -> ch + hne2 = -0.5*||e||^2.  One wave per row.
// ---------------------------------------------------------------------------
__global__ __launch_bounds__(256) void vq_prep(
    const float* __restrict__ z, const float* __restrict__ cb,
    float* __restrict__ x2, float* __restrict__ hne2,
    unsigned short* __restrict__ zh, unsigned short* __restrict__ ch) {
    int wave = threadIdx.x >> 6;
    int lane = threadIdx.x & 63;
    int row  = blockIdx.x * 4 + wave;
    bool isZ = row < N_VEC;
    int lr = isZ ? row : row - N_VEC;
    const float* src = isZ ? z + (size_t)row * DIM : cb + (size_t)lr * DIM;

    const float4* s4 = (const float4*)src;
    float4 v0 = s4[lane * 2];
    float4 v1 = s4[lane * 2 + 1];
    float f[8] = {v0.x, v0.y, v0.z, v0.w, v1.x, v1.y, v1.z, v1.w};

    float s = 0.0f;
    ushort8 h8;
#pragma unroll
    for (int i = 0; i < 8; ++i) { s += f[i] * f[i]; h8[i] = f2bf(f[i]); }
    ((ushort8*)(isZ ? zh : ch))[(size_t)lr * 64 + lane] = h8;

#pragma unroll
    for (int off = 32; off >= 1; off >>= 1) s += __shfl_xor(s, off, 64);
    if (lane == 0) {
        if (isZ) x2[lr] = s;
        else     hne2[lr] = -0.5f * s;
    }
}

// ---------------------------------------------------------------------------
// Kernel 2: champion r0 skeleton (same tiles, staging, octet-XOR swizzle,
// barriers) with the MFMA shape swapped 16x16x32 -> 32x32x16 (2382 vs 2075 TF
// ubench: ~15% faster matrix pipe).  Per-wave 64x128 = 2 row-blocks x 4
// code-blocks of 32x32; acc = 2x4 f32x16 (128 regs, unchanged).
// C/D layout (m74/m101-verified): col = lane&31,
// row = (reg&3) + 8*(reg>>2) + 4*(lane>>5).
// Operand layout (analog of working 16x16 pattern): row = lane&31,
// k-octet (8 bf16) = lane>>5 within each K=16 slice.
// Fused top-2 via PACKED floats: low 11 mantissa bits replaced by
// tag = ct:4 | cn:2 | (lane&31):5.  State = 2x16 packed pairs, no indices.
// Partials: slot = half*2 + wN (4 slots/row) -> pP1/pP2.
// ---------------------------------------------------------------------------
__global__ __launch_bounds__(256, 2) void vq_gemm(
    const unsigned short* __restrict__ zh, const unsigned short* __restrict__ ch,
    const float* __restrict__ hne2,
    float* __restrict__ pP1, float* __restrict__ pP2) {
    __shared__ short8 AsC[1024];   // 128 rows x 8 octet-cells, XOR-swizzled (16 KB)
    __shared__ short8 BsC[2048];   // 256 codes x 8 octet-cells, XOR-swizzled (32 KB)

    const int tid  = threadIdx.x;
    const int w    = tid >> 6;
    const int lane = tid & 63;
    const int wM   = w & 1;
    const int wN   = w >> 1;
    const int rowBase   = blockIdx.x * 128;
    const int half      = blockIdx.y;
    const int codeBase0 = half * 4096;

    const int l31 = lane & 31, hi1 = lane >> 5;

    // staging offsets: UNCHANGED from champion r0
    unsigned aOff[4];
#pragma unroll
    for (int i = 0; i < 4; ++i) {
        int cell = (w * 4 + i) * 64 + lane;
        int r = cell >> 3, qs = cell & 7, q = qs ^ (r & 7);
        aOff[i] = ((unsigned)(rowBase + r) * DIM + q * 8) * 2;
    }
    unsigned bOff[8];
#pragma unroll
    for (int i = 0; i < 8; ++i) {
        int cell = (w * 8 + i) * 64 + lane;
        int c = cell >> 3, qs = cell & 7, q = qs ^ (c & 7);
        bOff[i] = ((unsigned)c * DIM + q * 8) * 2;   // relative to code-tile base
    }

    // fragment LDS cells: row r, K-slice ks reads octet qk = ks*2 + hi1,
    // stored at cell r*8 + (qk ^ (r&7))
    int baseA[2], xorA[2];
#pragma unroll
    for (int rm = 0; rm < 2; ++rm) {
        int rA = wM * 64 + rm * 32 + l31;
        baseA[rm] = rA * 8; xorA[rm] = rA & 7;
    }
    int baseB[4], xorB[4];
#pragma unroll
    for (int cn = 0; cn < 4; ++cn) {
        int rB = wN * 128 + cn * 32 + l31;
        baseB[cn] = rB * 8; xorB[cn] = rB & 7;
    }

    float g1v[2][16], g2v[2][16];
#pragma unroll
    for (int rm = 0; rm < 2; ++rm)
#pragma unroll
        for (int j = 0; j < 16; ++j) { g1v[rm][j] = -3.4e38f; g2v[rm][j] = -3.4e38f; }

    const char* pA = (const char*)zh;
    for (int ct = 0; ct < 16; ++ct) {
        const int codeBase = codeBase0 + ct * 256;
        const char* pB = (const char*)ch + (size_t)codeBase * (DIM * 2);
        float16x acc[2][4];
#pragma unroll
        for (int rm = 0; rm < 2; ++rm)
#pragma unroll
            for (int cn = 0; cn < 4; ++cn)
#pragma unroll
                for (int j = 0; j < 16; ++j) acc[rm][cn][j] = 0.0f;

        for (int dc = 0; dc < DIM; dc += 64) {
            const int dc2 = dc * 2;
            __syncthreads();
#pragma unroll
            for (int i = 0; i < 4; ++i)
                gl_lds16(pA + aOff[i] + dc2, &AsC[(w * 4 + i) * 64]);
#pragma unroll
            for (int i = 0; i < 8; ++i)
                gl_lds16(pB + bOff[i] + dc2, &BsC[(w * 8 + i) * 64]);
            __syncthreads();

#pragma unroll
            for (int ks = 0; ks < 4; ++ks) {
                const int qk = ks * 2 + hi1;
                short8 a[2], b[4];
#pragma unroll
                for (int rm = 0; rm < 2; ++rm) a[rm] = AsC[baseA[rm] + (qk ^ xorA[rm])];
#pragma unroll
                for (int cn = 0; cn < 4; ++cn) b[cn] = BsC[baseB[cn] + (qk ^ xorB[cn])];
#pragma unroll
                for (int cn = 0; cn < 4; ++cn)
#pragma unroll
                    for (int rm = 0; rm < 2; ++rm)
                        acc[rm][cn] = __builtin_amdgcn_mfma_f32_32x32x16_bf16(
                            a[rm], b[cn], acc[rm][cn], 0, 0, 0);
            }
        }

        // epilogue: packed running top-2 (med3+max), identity in low 11 bits
#pragma unroll
        for (int cn = 0; cn < 4; ++cn) {
            int nb = codeBase + wN * 128 + cn * 32 + l31;
            float hv = hne2[nb];
            unsigned tag = ((unsigned)ct << 7) | ((unsigned)cn << 5) | (unsigned)l31;
#pragma unroll
            for (int rm = 0; rm < 2; ++rm) {
#pragma unroll
                for (int j = 0; j < 16; ++j) {
                    float g  = acc[rm][cn][j] + hv;
                    float pk = __uint_as_float(
                        (__float_as_uint(g) & 0xFFFFF800u) | tag);
                    g2v[rm][j] = med3(pk, g1v[rm][j], g2v[rm][j]);
                    g1v[rm][j] = fmaxf(g1v[rm][j], pk);
                }
            }
        }
    }

    // cross-lane packed top-2 merge over the 32 lanes (l31) sharing each row
    // (hi1 fixed within each 32-half; offs 1..16 stay inside the half)
#pragma unroll
    for (int rm = 0; rm < 2; ++rm)
#pragma unroll
        for (int j = 0; j < 16; ++j) {
            float a1 = g1v[rm][j], a2 = g2v[rm][j];
#pragma unroll
            for (int off = 1; off <= 16; off <<= 1) {
                float b1 = __shfl_xor(a1, off, 64);
                float b2 = __shfl_xor(a2, off, 64);
                a2 = med3(b1, a1, a2);
                a1 = fmaxf(a1, b1);
                a2 = med3(b2, a1, a2);   // b2 <= b1 <= new a1: rank-1 safe
            }
            if (l31 == 0) {
                int row = rowBase + wM * 64 + rm * 32 +
                          (j & 3) + 8 * (j >> 2) + 4 * hi1;
                int slot = half * 2 + wN;          // 4 slots/row, race-free
                pP1[(size_t)slot * N_VEC + row] = a1;
                pP2[(size_t)slot * N_VEC + row] = a2;
            }
        }
}

// ---------------------------------------------------------------------------
// Kernel 3: merge 4 packed (g1,g2) pairs per row -> exact global top-2.
// Winner slot s1 tracked; code decoded from slot + 11-bit tag:
//   code = (s1>>1)*4096 + (tag>>7)*256 + (s1&1)*128 + ((tag>>5)&3)*32 + (tag&31)
// Packed ties across slots -> gap 0 -> flagged -> rescued exactly.
// pG is a SEPARATE buffer (no aliasing with pP1 -> no restrict UB).
// ---------------------------------------------------------------------------
__global__ __launch_bounds__(256) void vq_scan(
    const float* __restrict__ pP1, const float* __restrict__ pP2,
    float* __restrict__ pG, int* __restrict__ provIdx, int* __restrict__ flags,
    unsigned long long* __restrict__ keys,
    int* __restrict__ rescueRows, int* __restrict__ rescueCnt) {
    int r = blockIdx.x * 256 + threadIdx.x;
    float g1 = -3.4e38f, g2 = -3.4e38f;
    int   s1 = 0;
#pragma unroll
    for (int s = 0; s < 4; ++s) {
        float a1 = pP1[(size_t)s * N_VEC + r];
        float a2 = pP2[(size_t)s * N_VEC + r];
        if (a1 > g1) { g2 = g1; g1 = a1; s1 = s; }
        else         { g2 = fmaxf(g2, a1); }
        g2 = fmaxf(g2, a2);    // a2 <= a1: only competes for rank 2
    }
    unsigned u1 = __float_as_uint(g1);
    int t  = (int)(u1 & 0x7FFu);
    int n1 = (s1 >> 1) * 4096 + (t >> 7) * 256 + (s1 & 1) * 128 +
             ((t >> 5) & 3) * 32 + (t & 31);
    provIdx[r] = n1;
    pG[r] = __uint_as_float(u1 & 0xFFFFF800u);   // quantized best (for loss)
    int fl = (g1 - g2 < MARGIN) ? 1 : 0;
    flags[r] = fl;
    if (fl) {
        keys[r] = ~0ull;
        int p = atomicAdd(rescueCnt, 1);
        rescueRows[p] = r;
    }
}

// ---------------------------------------------------------------------------
// Kernel 4: exact fp32 rescue over ALL codes for flagged rows.
// grid (40, 32): y = 256-code chunk, x = row tiles (grid-stride; 40 covers
// ~2400 flagged rows at MARGIN 0.5 in one pass). Thread's 8 codes are
// tx + 32*j -> lane-consecutive, conflict-free LDS B reads.
// ---------------------------------------------------------------------------
#define RBM 64
#define RBK 256
#define RBD 32

__global__ __launch_bounds__(256, 2) void vq_rescue(
    const float* __restrict__ z, const float* __restrict__ cb,
    const float* __restrict__ hne2,
    const int* __restrict__ rescueRows, const int* __restrict__ rescueCnt,
    unsigned long long* __restrict__ keys) {
    __shared__ float As[RBD][RBM];   // 8 KB, transposed
    __shared__ float Bs[RBD][RBK];   // 32 KB, transposed
    __shared__ int   rowOf[RBM];

    const int tid = threadIdx.x;
    const int tx  = tid & 31;
    const int ty  = tid >> 5;
    const int cnt = *rescueCnt;
    const int codeBase = blockIdx.y * RBK;       // grid.y = 32
    const int sRow = tid >> 2;
    const int sQ   = tid & 3;

    for (int rt = blockIdx.x; rt * RBM < cnt; rt += gridDim.x) {
        const int slotBase = rt * RBM;
        __syncthreads();   // prior iteration fully done before rowOf/tiles change
        if (tid < RBM) rowOf[tid] = rescueRows[slotBase + tid];
        __syncthreads();

        float acc[8][8];
#pragma unroll
        for (int i = 0; i < 8; ++i)
#pragma unroll
            for (int j = 0; j < 8; ++j) acc[i][j] = 0.0f;

        for (int dc = 0; dc < DIM; dc += RBD) {
            __syncthreads();
            {   // stage A (indirected rows)
                const float* srcA = z + (size_t)rowOf[sRow] * DIM + dc + sQ * 8;
                float4 va0 = ((const float4*)srcA)[0];
                float4 va1 = ((const float4*)srcA)[1];
                int c0 = sQ * 8;
                As[c0 + 0][sRow] = va0.x; As[c0 + 1][sRow] = va0.y;
                As[c0 + 2][sRow] = va0.z; As[c0 + 3][sRow] = va0.w;
                As[c0 + 4][sRow] = va1.x; As[c0 + 5][sRow] = va1.y;
                As[c0 + 6][sRow] = va1.z; As[c0 + 7][sRow] = va1.w;
            }
            {   // stage B: one code per thread
                const float4* srcB = (const float4*)(cb + (size_t)(codeBase + tid) * DIM + dc);
#pragma unroll
                for (int j = 0; j < 8; ++j) {
                    float4 v = srcB[j];
                    Bs[j * 4 + 0][tid] = v.x; Bs[j * 4 + 1][tid] = v.y;
                    Bs[j * 4 + 2][tid] = v.z; Bs[j * 4 + 3][tid] = v.w;
                }
            }
            __syncthreads();

#pragma unroll
            for (int d = 0; d < RBD; ++d) {
                float a[8], b[8];
                *(float4*)&a[0] = *(const float4*)&As[d][ty * 8];
                *(float4*)&a[4] = *(const float4*)&As[d][ty * 8 + 4];
#pragma unroll
                for (int j = 0; j < 8; ++j) b[j] = Bs[d][tx + 32 * j];
#pragma unroll
                for (int i = 0; i < 8; ++i)
#pragma unroll
                    for (int j = 0; j < 8; ++j) acc[i][j] += a[i] * b[j];
            }
        }

        float best[8];
        int   bidx[8];
#pragma unroll
        for (int i = 0; i < 8; ++i) { best[i] = 3.4e38f; bidx[i] = K_CODES; }

#pragma unroll
        for (int j = 0; j < 8; ++j) {
            int code = codeBase + tx + 32 * j;
            float ev = -hne2[code];               // = e2/2
#pragma unroll
            for (int i = 0; i < 8; ++i) {
                float kv = ev - acc[i][j];        // = e2/2 - x.e  (> 0)
                if (kv < best[i] || (kv == best[i] && code < bidx[i])) {
                    best[i] = kv;
                    bidx[i] = code;
                }
            }
        }

        // reduce argmin across the 32 tx-lanes sharing each row group
#pragma unroll
        for (int off = 16; off >= 1; off >>= 1) {
#pragma unroll
            for (int i = 0; i < 8; ++i) {
                float od = __shfl_xor(best[i], off, 64);
                int   oi = __shfl_xor(bidx[i], off, 64);
                if (od < best[i] || (od == best[i] && oi < bidx[i])) {
                    best[i] = od;
                    bidx[i] = oi;
                }
            }
        }

        if (tx == 0) {
#pragma unroll
            for (int i = 0; i < 8; ++i) {
                int slot = slotBase + ty * 8 + i;
                if (slot < cnt) {
                    unsigned long long key =
                        ((unsigned long long)__float_as_uint(best[i]) << 32) |
                        (unsigned long long)(unsigned)bidx[i];
                    atomicMin(&keys[rowOf[ty * 8 + i]], key);
                }
            }
        }
    }
}

// ---------------------------------------------------------------------------
// Kernel 5: final per-row results: index, counts, loss partial, z_q gather.
// ---------------------------------------------------------------------------
__global__ __launch_bounds__(256) void vq_final(
    const float* __restrict__ gBest, const int* __restrict__ provIdx,
    const int* __restrict__ flags, const unsigned long long* __restrict__ keys,
    const float* __restrict__ x2, const float* __restrict__ cb,
    float* __restrict__ zq, float* __restrict__ idxf,
    float* __restrict__ counts, float* __restrict__ lossAcc) {
    __shared__ int   sIdx[256];
    __shared__ float wsum[4];
    const int tid = threadIdx.x;
    const int r   = blockIdx.x * 256 + tid;

    int n; float dist;
    if (flags[r]) {
        unsigned long long k = keys[r];
        n = (int)(unsigned)(k & 0xffffffffu);
        float kv = __uint_as_float((unsigned)(k >> 32));
        dist = x2[r] + 2.0f * kv;          // x2 + e2 - 2 x.e
    } else {
        n = provIdx[r];
        dist = x2[r] - 2.0f * gBest[r];
    }
    sIdx[tid] = n;
    idxf[r]   = (float)n;
    atomicAdd(&counts[n], 1.0f);

    float ls = dist;
#pragma unroll
    for (int off = 32; off >= 1; off >>= 1) ls += __shfl_xor(ls, off, 64);
    if ((tid & 63) == 0) wsum[tid >> 6] = ls;
    __syncthreads();
    if (tid == 0) atomicAdd(lossAcc, wsum[0] + wsum[1] + wsum[2] + wsum[3]);

    const float4* cb4 = (const float4*)cb;
    float4* zq4 = (float4*)(zq + (size_t)blockIdx.x * 256 * DIM);
    for (int t = tid; t < 256 * (DIM / 4); t += 256) {
        int row = t >> 7, f4 = t & 127;
        zq4[(size_t)row * 128 + f4] = cb4[(size_t)sIdx[row] * 128 + f4];
    }
}

// ---------------------------------------------------------------------------
// Kernel 6: finalize scalars
// ---------------------------------------------------------------------------
__global__ __launch_bounds__(256) void vq_finalize(const float* __restrict__ counts,
                                                   const float* __restrict__ lossAcc,
                                                   float* __restrict__ out_loss,
                                                   float* __restrict__ out_perp) {
    __shared__ float wsum[4];
    int tid = threadIdx.x;
    float s = 0.0f;
    for (int i = tid; i < K_CODES; i += 256) {
        float p = counts[i] * (1.0f / (float)N_VEC);
        s += p * logf(p + 1e-10f);
    }
#pragma unroll
    for (int off = 32; off >= 1; off >>= 1) s += __shfl_xor(s, off, 64);
    if ((tid & 63) == 0) wsum[tid >> 6] = s;
    __syncthreads();
    if (tid == 0) {
        *out_perp = expf(-(wsum[0] + wsum[1] + wsum[2] + wsum[3]));
        *out_loss = 1.25f * lossAcc[0] / (float)(N_VEC * DIM);
    }
}

// ---------------------------------------------------------------------------
// ws layout (bytes), identical footprint to r0:
//   x2 @0 131072 | hne2 @131072 32768 | counts @163840 32768 | lossAcc @196608 4
//   rescueCnt @196612 4 | provIdx @262144 131072 | flags @393216 131072
//   keys @524288 262144 | rescueRows @786432 131072
//   pP1 @1048576 524288 | pG @1572864 131072 | pP2 @2097152 524288
//   zh @2621440 33554432 | ch @36175872 8388608
// ---------------------------------------------------------------------------
extern "C" void kernel_launch(void* const* d_in, const int* in_sizes, int n_in,
                              void* d_out, int out_size, void* d_ws, size_t ws_size,
                              hipStream_t stream) {
    (void)in_sizes; (void)n_in; (void)out_size; (void)ws_size;
    const float* z  = (const float*)d_in[0];
    const float* cb = (const float*)d_in[1];

    char* ws = (char*)d_ws;
    float* x2        = (float*)(ws + 0);
    float* hne2      = (float*)(ws + 131072);
    float* counts    = (float*)(ws + 163840);
    float* lossAcc   = (float*)(ws + 196608);
    int*   rescueCnt = (int*)  (ws + 196612);
    int*   provIdx   = (int*)  (ws + 262144);
    int*   flags     = (int*)  (ws + 393216);
    unsigned long long* keys = (unsigned long long*)(ws + 524288);
    int*   rescueRows = (int*) (ws + 786432);
    float* pP1       = (float*)(ws + 1048576);
    float* pG        = (float*)(ws + 1572864);
    float* pP2       = (float*)(ws + 2097152);
    unsigned short* zh = (unsigned short*)(ws + 2621440);
    unsigned short* ch = (unsigned short*)(ws + 36175872);

    float* out      = (float*)d_out;
    float* zq       = out;
    float* out_loss = out + 16777216;
    float* idxf     = out + 16777217;
    float* out_perp = out + 16777217 + 32768;

    // zero counts + lossAcc + rescueCnt (contiguous) and rescueRows
    hipMemsetAsync(counts, 0, 32768 + 8, stream);
    hipMemsetAsync(rescueRows, 0, 131072, stream);
    vq_prep<<<(N_VEC + K_CODES) / 4, 256, 0, stream>>>(z, cb, x2, hne2, zh, ch);
    dim3 grid(N_VEC / 128, 2);
    vq_gemm<<<grid, 256, 0, stream>>>(zh, ch, hne2, pP1, pP2);
    vq_scan<<<N_VEC / 256, 256, 0, stream>>>(pP1, pP2, pG, provIdx, flags, keys,
                                             rescueRows, rescueCnt);
    dim3 rgrid(40, 32);
    vq_rescue<<<rgrid, 256, 0, stream>>>(z, cb, hne2, rescueRows, rescueCnt, keys);
    vq_final<<<N_VEC / 256, 256, 0, stream>>>(pG, provIdx, flags, keys, x2, cb,
                                              zq, idxf, counts, lossAcc);
    vq_finalize<<<1, 256, 0, stream>>>(counts, lossAcc, out_loss, out_perp);
}